// Round 1
// baseline (15058.936 us; speedup 1.0000x reference)
//
#include <hip/hip_runtime.h>

#define TPB 256

// ---------------- edge list construction ----------------
__global__ void build_edges_k(const int* __restrict__ ea, const int* __restrict__ eb,
                              const int* __restrict__ pb,
                              int Ea, int Eb, int NC, int Na,
                              int* __restrict__ src, int* __restrict__ dst) {
    int e = blockIdx.x * TPB + threadIdx.x;
    int E = Ea + Eb + 2 * NC;
    if (e >= E) return;
    int s, d;
    if (e < Ea) { s = ea[2*e]; d = ea[2*e+1]; }
    else if (e < Ea + Eb) { int i = e - Ea; s = eb[2*i] + Na; d = eb[2*i+1] + Na; }
    else if (e < Ea + Eb + NC) { int c = e - Ea - Eb; s = pb[c]; d = pb[NC + c] + Na; }
    else { int c = e - Ea - Eb - NC; s = pb[NC + c] + Na; d = pb[c]; }
    src[e] = s; dst[e] = d;
}

// ---------------- h0 = relu([x[src], ef] @ W_in + b_in), fused scatter of h_1=h0 ----------------
__global__ void h0_scatter_k(const float* __restrict__ xa, const float* __restrict__ xb,
                             const float* __restrict__ efa, const float* __restrict__ efb,
                             const int* __restrict__ src, const int* __restrict__ dst,
                             int Ea, int Eb, int Na, int E,
                             const float* __restrict__ W_in, const float* __restrict__ b_in,
                             float* __restrict__ h0, float* __restrict__ agg) {
    __shared__ float Wl[6 * 64];
    __shared__ float bl[64];
    for (int t = threadIdx.x; t < 6 * 64; t += TPB) Wl[t] = W_in[t];
    if (threadIdx.x < 64) bl[threadIdx.x] = b_in[threadIdx.x];
    __syncthreads();
    int gid = blockIdx.x * TPB + threadIdx.x;
    if (gid >= E * 64) return;
    int e = gid >> 6, j = gid & 63;
    int s = src[e];
    const float* xp = (s < Na) ? (xa + (size_t)s * 5) : (xb + (size_t)(s - Na) * 5);
    float efv = (e < Ea) ? efa[e] : ((e < Ea + Eb) ? efb[e - Ea] : 999.0f);
    float acc = bl[j];
    #pragma unroll
    for (int i = 0; i < 5; i++) acc += xp[i] * Wl[i * 64 + j];
    acc += efv * Wl[5 * 64 + j];
    acc = fmaxf(acc, 0.0f);
    h0[gid] = acc;
    atomicAdd(&agg[(size_t)dst[e] * 64 + j], acc);
}

// ---------------- aggW = agg @ W_msg + b_msg (per node); also zeroes agg for next step ----------------
__global__ __launch_bounds__(TPB) void node_k(float* __restrict__ agg,
                                              const float* __restrict__ W_msg,
                                              const float* __restrict__ b_msg,
                                              float* __restrict__ aggW, int N) {
    __shared__ __align__(16) float Wl[64 * 64];
    __shared__ float bl[64];
    __shared__ __align__(16) float actL[64 * 64];
    int tid = threadIdx.x;
    for (int t = tid; t < 4096; t += TPB) Wl[t] = W_msg[t];
    if (tid < 64) bl[tid] = b_msg[tid];
    size_t base = (size_t)blockIdx.x * 4096;
    size_t lim = (size_t)N * 64;
    for (int t = tid; t < 4096; t += TPB) {
        size_t g = base + t;
        float v = 0.0f;
        if (g < lim) { v = agg[g]; agg[g] = 0.0f; }
        actL[t] = v;
    }
    __syncthreads();
    int j = tid & 63;
    int grp = tid >> 6;        // 0..3 -> 16 node rows each
    int n0 = grp * 16;
    float acc[16];
    #pragma unroll
    for (int k = 0; k < 16; k++) acc[k] = bl[j];
    const float4* act4 = (const float4*)actL;
    for (int i4 = 0; i4 < 16; i4++) {
        float w0 = Wl[(4 * i4 + 0) * 64 + j];
        float w1 = Wl[(4 * i4 + 1) * 64 + j];
        float w2 = Wl[(4 * i4 + 2) * 64 + j];
        float w3 = Wl[(4 * i4 + 3) * 64 + j];
        #pragma unroll
        for (int k = 0; k < 16; k++) {
            float4 a = act4[(n0 + k) * 16 + i4];
            acc[k] += a.x * w0 + a.y * w1 + a.z * w2 + a.w * w3;
        }
    }
    #pragma unroll
    for (int k = 0; k < 16; k++) {
        size_t g2 = base + (size_t)(n0 + k) * 64 + j;
        if (g2 < lim) aggW[g2] = acc[k];
    }
}

// ---------------- edge update: h_new = relu(h0 + aggW[src]); scatter into agg ----------------
__global__ void edge_step_k(const float* __restrict__ h0, const float* __restrict__ aggW,
                            const int* __restrict__ src, const int* __restrict__ dst,
                            float* __restrict__ agg, int E) {
    int gid = blockIdx.x * TPB + threadIdx.x;
    if (gid >= E * 64) return;
    int e = gid >> 6, j = gid & 63;
    float v = h0[gid] + aggW[(size_t)src[e] * 64 + j];
    v = fmaxf(v, 0.0f);
    atomicAdd(&agg[(size_t)dst[e] * 64 + j], v);
}

__global__ void edge_final_k(const float* __restrict__ h0, const float* __restrict__ aggW,
                             const int* __restrict__ src, const int* __restrict__ dst,
                             float* __restrict__ agg, float* __restrict__ hsave,
                             int E, int off) {
    int gid = blockIdx.x * TPB + threadIdx.x;
    if (gid >= E * 64) return;
    int e = gid >> 6, j = gid & 63;
    float v = h0[gid] + aggW[(size_t)src[e] * 64 + j];
    v = fmaxf(v, 0.0f);
    atomicAdd(&agg[(size_t)dst[e] * 64 + j], v);
    if (e >= off) hsave[(size_t)(e - off) * 64 + j] = v;
}

// ---------------- node_h = relu([x, aggF] @ W_node + b_node) ----------------
__global__ void nodeh_k(const float* __restrict__ xa, const float* __restrict__ xb,
                        int Na, int N,
                        const float* __restrict__ agg,
                        const float* __restrict__ W_node, const float* __restrict__ b_node,
                        float* __restrict__ node_h) {
    __shared__ float Wl[69 * 32];
    __shared__ float bl[32];
    for (int t = threadIdx.x; t < 69 * 32; t += TPB) Wl[t] = W_node[t];
    if (threadIdx.x < 32) bl[threadIdx.x] = b_node[threadIdx.x];
    __syncthreads();
    int gid = blockIdx.x * TPB + threadIdx.x;
    if (gid >= N * 32) return;
    int n = gid >> 5, j = gid & 31;
    const float* xp = (n < Na) ? (xa + (size_t)n * 5) : (xb + (size_t)(n - Na) * 5);
    float acc = bl[j];
    #pragma unroll
    for (int i = 0; i < 5; i++) acc += xp[i] * Wl[i * 32 + j];
    const float4* a4 = (const float4*)(agg + (size_t)n * 64);
    #pragma unroll
    for (int i4 = 0; i4 < 16; i4++) {
        float4 a = a4[i4];
        acc += a.x * Wl[(5 + 4 * i4 + 0) * 32 + j];
        acc += a.y * Wl[(5 + 4 * i4 + 1) * 32 + j];
        acc += a.z * Wl[(5 + 4 * i4 + 2) * 32 + j];
        acc += a.w * Wl[(5 + 4 * i4 + 3) * 32 + j];
    }
    node_h[gid] = fmaxf(acc, 0.0f);
}

// ---------------- MLP head ----------------
#define TM 24
#define MSTR 260  // floats; 1040 bytes, 16B aligned rows

__device__ __forceinline__ void mlp_layer(const float* __restrict__ W, const float* __restrict__ b,
                                          int in_dim, int out_dim,
                                          const float* __restrict__ A, float* __restrict__ B) {
    for (int idx = threadIdx.x; idx < TM * out_dim; idx += TPB) {
        int r = idx / out_dim;
        int j = idx - r * out_dim;
        float acc = b[j];
        const float4* a4 = (const float4*)(A + r * MSTR);
        for (int i4 = 0; i4 < (in_dim >> 2); i4++) {
            float4 a = a4[i4];
            acc += a.x * W[(4 * i4 + 0) * out_dim + j];
            acc += a.y * W[(4 * i4 + 1) * out_dim + j];
            acc += a.z * W[(4 * i4 + 2) * out_dim + j];
            acc += a.w * W[(4 * i4 + 3) * out_dim + j];
        }
        B[r * MSTR + j] = fmaxf(acc, 0.0f);
    }
    __syncthreads();
}

__global__ __launch_bounds__(TPB) void mlp_k(const float* __restrict__ node_h,
                                             const float* __restrict__ hsave,
                                             const int* __restrict__ pb, int NC, int Na,
                                             const float* __restrict__ W1, const float* __restrict__ b1,
                                             const float* __restrict__ W2, const float* __restrict__ b2,
                                             const float* __restrict__ W3, const float* __restrict__ b3,
                                             const float* __restrict__ W4, const float* __restrict__ b4,
                                             const float* __restrict__ W5, const float* __restrict__ b5,
                                             const float* __restrict__ W6, const float* __restrict__ b6,
                                             float* __restrict__ out) {
    __shared__ __align__(16) float A[TM * MSTR];
    __shared__ __align__(16) float B[TM * MSTR];
    int c0 = blockIdx.x * TM;
    for (int idx = threadIdx.x; idx < TM * 128; idx += TPB) {
        int r = idx >> 7, col = idx & 127;
        int c = c0 + r;
        float v = 0.0f;
        if (c < NC) {
            if (col < 32) v = node_h[(size_t)pb[c] * 32 + col];
            else if (col < 64) v = node_h[(size_t)(Na + pb[NC + c]) * 32 + (col - 32)];
            else v = hsave[(size_t)c * 64 + (col - 64)] + hsave[(size_t)(NC + c) * 64 + (col - 64)];
        }
        A[r * MSTR + col] = v;
    }
    __syncthreads();
    mlp_layer(W1, b1, 128, 128, A, B);
    mlp_layer(W2, b2, 128, 256, B, A);
    mlp_layer(W3, b3, 256, 256, A, B);
    mlp_layer(W4, b4, 256, 128, B, A);
    mlp_layer(W5, b5, 128, 64, A, B);
    if (threadIdx.x < TM) {
        int r = threadIdx.x, c = c0 + r;
        if (c < NC) {
            float z[4];
            #pragma unroll
            for (int k = 0; k < 4; k++) {
                float acc = b6[k];
                for (int i = 0; i < 64; i++) acc += B[r * MSTR + i] * W6[i * 4 + k];
                z[k] = acc;
            }
            float m = fmaxf(fmaxf(z[0], z[1]), fmaxf(z[2], z[3]));
            float e0 = expf(z[0] - m), e1 = expf(z[1] - m), e2 = expf(z[2] - m), e3 = expf(z[3] - m);
            float inv = 1.0f / (e0 + e1 + e2 + e3);
            int am = 0; float bm = z[0];
            if (z[1] > bm) { bm = z[1]; am = 1; }
            if (z[2] > bm) { bm = z[2]; am = 2; }
            if (z[3] > bm) { bm = z[3]; am = 3; }
            out[(size_t)c * 3 + 0] = (float)pb[c];
            out[(size_t)c * 3 + 1] = (float)pb[NC + c];
            out[(size_t)c * 3 + 2] = (float)am;
            float* po = out + (size_t)NC * 3 + (size_t)c * 4;
            po[0] = e0 * inv; po[1] = e1 * inv; po[2] = e2 * inv; po[3] = e3 * inv;
        }
    }
}

extern "C" void kernel_launch(void* const* d_in, const int* in_sizes, int n_in,
                              void* d_out, int out_size, void* d_ws, size_t ws_size,
                              hipStream_t stream) {
    const float* xa   = (const float*)d_in[0];
    const float* efa  = (const float*)d_in[1];
    const int*   ea   = (const int*)d_in[2];
    const float* xb   = (const float*)d_in[3];
    const float* efb  = (const float*)d_in[4];
    const int*   eb   = (const int*)d_in[5];
    const int*   pb   = (const int*)d_in[6];
    const float* W_in   = (const float*)d_in[7];
    const float* b_in   = (const float*)d_in[8];
    const float* W_msg  = (const float*)d_in[9];
    const float* b_msg  = (const float*)d_in[10];
    const float* W_node = (const float*)d_in[11];
    const float* b_node = (const float*)d_in[12];
    const float* W1 = (const float*)d_in[13]; const float* b1 = (const float*)d_in[14];
    const float* W2 = (const float*)d_in[15]; const float* b2 = (const float*)d_in[16];
    const float* W3 = (const float*)d_in[17]; const float* b3 = (const float*)d_in[18];
    const float* W4 = (const float*)d_in[19]; const float* b4 = (const float*)d_in[20];
    const float* W5 = (const float*)d_in[21]; const float* b5 = (const float*)d_in[22];
    const float* W6 = (const float*)d_in[23]; const float* b6 = (const float*)d_in[24];

    int Na = in_sizes[0] / 5;
    int Ea = in_sizes[2] / 2;
    int Nb = in_sizes[3] / 5;
    int Eb = in_sizes[5] / 2;
    int NC = in_sizes[6] / 2;
    int N = Na + Nb;
    int E = Ea + Eb + 2 * NC;
    int off = Ea + Eb;

    char* p = (char*)d_ws;
    auto alloc = [&](size_t bytes) { char* r = p; p += (bytes + 255) & ~(size_t)255; return r; };
    int*   src   = (int*)alloc((size_t)E * 4);
    int*   dst   = (int*)alloc((size_t)E * 4);
    float* h0    = (float*)alloc((size_t)E * 64 * 4);
    float* agg   = (float*)alloc((size_t)N * 64 * 4);
    float* aggW  = (float*)alloc((size_t)N * 64 * 4);
    float* hsave = (float*)alloc((size_t)2 * NC * 64 * 4);
    float* nodeh = (float*)alloc((size_t)N * 32 * 4);
    if ((size_t)(p - (char*)d_ws) > ws_size) return;  // insufficient workspace -> visible failure

    hipMemsetAsync(agg, 0, (size_t)N * 64 * 4, stream);
    build_edges_k<<<(E + TPB - 1) / TPB, TPB, 0, stream>>>(ea, eb, pb, Ea, Eb, NC, Na, src, dst);
    int egrid = (E * 64 + TPB - 1) / TPB;
    h0_scatter_k<<<egrid, TPB, 0, stream>>>(xa, xb, efa, efb, src, dst, Ea, Eb, Na, E, W_in, b_in, h0, agg);
    int ngrid = (N + 63) / 64;
    for (int t = 1; t <= 100; t++) {
        node_k<<<ngrid, TPB, 0, stream>>>(agg, W_msg, b_msg, aggW, N);
        if (t < 100)
            edge_step_k<<<egrid, TPB, 0, stream>>>(h0, aggW, src, dst, agg, E);
        else
            edge_final_k<<<egrid, TPB, 0, stream>>>(h0, aggW, src, dst, agg, hsave, E, off);
    }
    nodeh_k<<<((size_t)N * 32 + TPB - 1) / TPB, TPB, 0, stream>>>(xa, xb, Na, N, agg, W_node, b_node, nodeh);
    mlp_k<<<(NC + TM - 1) / TM, TPB, 0, stream>>>(nodeh, hsave, pb, NC, Na,
                                                  W1, b1, W2, b2, W3, b3, W4, b4, W5, b5, W6, b6,
                                                  (float*)d_out);
}